// Round 7
// baseline (42.459 us; speedup 1.0000x reference)
//
#include <hip/hip_runtime.h>

// RandomFilter: per-image 3x3 depthwise correlation, impulse at [2,2].
// img: [32, 3, 512, 512] fp32; noise: [32, 3, 3] fp32.
// out[b,c,h,w] = clip( sum img_pad[h+kh-1][w+kw-1] * (0.1*noise[b] + delta22)[kh][kw], 0, 1 )
//
// R7: rolling-row software pipeline. Wave = 8-row x 512-col band (lane = 8-col
// group). Per output row: ONE new input row load (2 dense float4; halo columns
// via __shfl_up/down of neighbor lanes -> load instrs halved vs R3, zero halo
// re-fetch), 10-float window ring (3 rows, static indices), compute, store.
// Loads pinned early with sched_barrier(0) so the compiler can't re-sink them
// (R6 failed exactly that way: VGPR 52 proved the 24-load hoist was undone).
// 1536 blocks -> 24 waves/CU; ~3 rows in flight/wave at prologue, 1 full
// compute iteration (~72 FMA) between issue and use in steady state.

#define RF_H 512
#define RF_W 512
#define RF_SIGMA 0.1f

typedef float floatx4 __attribute__((ext_vector_type(4)));

__device__ __forceinline__ void build_win(floatx4 Bv, floatx4 Cv,
                                          float mA, float mD, float zf,
                                          float* w) {
    const float left  = __shfl_up(Cv.w, 1);    // lane-1's in[w0-1]
    const float right = __shfl_down(Bv.x, 1);  // lane+1's in[w0+8]
    w[0] = left * mA * zf;
    w[1] = Bv.x * zf; w[2] = Bv.y * zf; w[3] = Bv.z * zf; w[4] = Bv.w * zf;
    w[5] = Cv.x * zf; w[6] = Cv.y * zf; w[7] = Cv.z * zf; w[8] = Cv.w * zf;
    w[9] = right * mD * zf;
}

__global__ __launch_bounds__(256) void RandomFilter_40767829574170_kernel(
    const float* __restrict__ img,
    const float* __restrict__ noise,
    float* __restrict__ out)
{
    const int tid   = threadIdx.x;
    const int lane  = tid & 63;
    const int wave  = tid >> 6;                      // 0..3
    const int plane = blockIdx.x >> 4;               // 16 blocks/plane
    const int band  = ((blockIdx.x & 15) << 2) | wave;  // 0..63
    const int h0    = band << 3;                     // 8 output rows per wave
    const int b     = plane / 3;

    const float* P = img + plane * (RF_H * RF_W);
    float*       O = out + plane * (RF_H * RF_W);
    const int    w0 = lane << 3;

    const float mA = (lane > 0)  ? 1.0f : 0.0f;
    const float mD = (lane < 63) ? 1.0f : 0.0f;
    const float ztop = (h0 == 0)          ? 0.0f : 1.0f;
    const float zbot = (h0 + 8 == RF_H)   ? 0.0f : 1.0f;

    // 3x3 weight from noise (uniform, L1/L2 hit).
    const float* np_ = noise + b * 9;
    float wgt[3][3];
    #pragma unroll
    for (int r = 0; r < 3; ++r)
        #pragma unroll
        for (int s = 0; s < 3; ++s)
            wgt[r][s] = RF_SIGMA * np_[r * 3 + s];
    wgt[2][2] += 1.0f;  // impulse at [2,2] (center = ceil(K/2))

#define LOADROW(hr, Bv, Cv)                                                   \
    {                                                                         \
        const int hrc = (hr) < 0 ? 0 : ((hr) > RF_H - 1 ? RF_H - 1 : (hr));   \
        const float* row_ = P + (hrc << 9);                                   \
        Bv = *reinterpret_cast<const floatx4*>(row_ + w0);                    \
        Cv = *reinterpret_cast<const floatx4*>(row_ + w0 + 4);                \
    }

    // ---- Prologue: 3 rows in flight before any compute. ----
    floatx4 aB, aC, bB, bC, pB, pC, nB, nC;
    LOADROW(h0 - 1, aB, aC);
    LOADROW(h0,     bB, bC);
    LOADROW(h0 + 1, pB, pC);
    __builtin_amdgcn_sched_barrier(0);   // pin the 3 prologue loads early

    float W[3][10];                      // window ring, slot(r) = (r+1)%3
    build_win(aB, aC, mA, mD, ztop, W[0]);   // row h0-1 (zero if top band)
    build_win(bB, bC, mA, mD, 1.0f, W[1]);   // row h0

    #pragma unroll
    for (int k = 0; k < 8; ++k) {        // output row h0+k
        // 1. issue next prefetch (row h0+k+2) BEFORE compute; pin it.
        if (k < 7) { LOADROW(h0 + k + 2, nB, nC); }
        __builtin_amdgcn_sched_barrier(0);

        // 2. build window of row h0+k+1 (loaded one iteration ago).
        const float zf = (k == 7) ? zbot : 1.0f;   // k compile-time
        build_win(pB, pC, mA, mD, zf, W[(k + 2) % 3]);
        pB = nB; pC = nC;                // rotate (register rename)

        // 3. compute: rows k-1,k,k+1 -> slots k%3,(k+1)%3,(k+2)%3.
        const float* Wm = W[k % 3];
        const float* Wc = W[(k + 1) % 3];
        const float* Wp = W[(k + 2) % 3];
        float acc[8];
        #pragma unroll
        for (int j = 0; j < 8; ++j) {
            acc[j] = wgt[0][0] * Wm[j] + wgt[0][1] * Wm[j + 1] + wgt[0][2] * Wm[j + 2]
                   + wgt[1][0] * Wc[j] + wgt[1][1] * Wc[j + 1] + wgt[1][2] * Wc[j + 2]
                   + wgt[2][0] * Wp[j] + wgt[2][1] * Wp[j + 1] + wgt[2][2] * Wp[j + 2];
        }

        // 4. clip + store (finite inputs -> NaN branch of reference is dead).
        floatx4 lo, hi;
        lo.x = fminf(fmaxf(acc[0], 0.0f), 1.0f);
        lo.y = fminf(fmaxf(acc[1], 0.0f), 1.0f);
        lo.z = fminf(fmaxf(acc[2], 0.0f), 1.0f);
        lo.w = fminf(fmaxf(acc[3], 0.0f), 1.0f);
        hi.x = fminf(fmaxf(acc[4], 0.0f), 1.0f);
        hi.y = fminf(fmaxf(acc[5], 0.0f), 1.0f);
        hi.z = fminf(fmaxf(acc[6], 0.0f), 1.0f);
        hi.w = fminf(fmaxf(acc[7], 0.0f), 1.0f);
        float* orow = O + ((h0 + k) << 9) + w0;
        *reinterpret_cast<floatx4*>(orow)     = lo;
        *reinterpret_cast<floatx4*>(orow + 4) = hi;
    }
#undef LOADROW
}

extern "C" void kernel_launch(void* const* d_in, const int* in_sizes, int n_in,
                              void* d_out, int out_size, void* d_ws, size_t ws_size,
                              hipStream_t stream) {
    const float* img   = (const float*)d_in[0];
    const float* noise = (const float*)d_in[1];
    float* out = (float*)d_out;

    // 96 planes * 16 blocks/plane = 1536 blocks; wave = 8-row band.
    RandomFilter_40767829574170_kernel<<<1536, 256, 0, stream>>>(img, noise, out);
}

// Round 8
// 36.129 us; speedup vs baseline: 1.1752x; 1.1752x over previous
//
#include <hip/hip_runtime.h>

// RandomFilter: per-image 3x3 depthwise correlation, impulse at [2,2].
// img: [32, 3, 512, 512] fp32; noise: [32, 3, 3] fp32.
// out[b,c,h,w] = clip( sum img_pad[h+kh-1][w+kw-1] * (0.1*noise[b] + delta22)[kh][kw], 0, 1 )
//
// R8 = R3's 4-row x 8-col tile (best so far, 39.5 us)
//    + shfl halo (R7's trick): left/right columns come from neighbor lanes,
//      so per input row only 2 dense float4 loads (24 -> 12 loads/thread)
//    + T1 XCD-chunked block swizzle (3072 = 8 x 384, bijective): a plane's 32
//      blocks stay on one XCD so the 2 shared halo rows between adjacent
//      16-row block bands hit that XCD's L2 instead of being re-fetched
//      from L3/HBM by a different chiplet.
// Evidence so far: occ 65/33/9%, VGPR 20/64/164, loads 4.5/0.75/0.63 per
// output -> all 40+-2 us. This round tests the last lever (cross-XCD halo
// traffic); if neutral, we are at the mixed-stream HBM wall (~153 MB/replay:
// 55 MB fill-thrashed input re-fetch + 98 MB writes, plus fill writeback
// drain) and that is the roofline.

#define RF_H 512
#define RF_W 512
#define RF_SIGMA 0.1f

typedef float floatx4 __attribute__((ext_vector_type(4)));

__global__ __launch_bounds__(256) void RandomFilter_40767829574170_kernel(
    const float* __restrict__ img,
    const float* __restrict__ noise,
    float* __restrict__ out)
{
    // XCD-chunked bijective swizzle: 3072 blocks, 8 XCDs, 384 blocks each.
    const int orig = blockIdx.x;
    const int bid  = (orig & 7) * 384 + (orig >> 3);

    const int idx   = bid * 256 + threadIdx.x;
    const int lane  = idx & 63;            // 8-col group == lane
    const int strip = (idx >> 6) & 127;    // 4-row strip
    const int plane = idx >> 13;           // 0..95 (b*3 + c)
    const int b     = plane / 3;

    const float* P  = img + plane * (RF_H * RF_W);
    const int    w0 = lane << 3;
    const int    h0 = strip << 2;

    const float mA = (lane > 0)  ? 1.0f : 0.0f;   // plane-left edge
    const float mD = (lane < 63) ? 1.0f : 0.0f;   // plane-right edge

    // 3x3 weight from noise (uniform, L1/L2 hit).
    const float* np_ = noise + b * 9;
    float wgt[3][3];
    #pragma unroll
    for (int r = 0; r < 3; ++r)
        #pragma unroll
        for (int s = 0; s < 3; ++s)
            wgt[r][s] = RF_SIGMA * np_[r * 3 + s];
    wgt[2][2] += 1.0f;  // impulse at [2,2] (center = ceil(K/2))

    float acc[4][8];
    #pragma unroll
    for (int o = 0; o < 4; ++o)
        #pragma unroll
        for (int j = 0; j < 8; ++j) acc[o][j] = 0.0f;

    #pragma unroll
    for (int r = 0; r < 6; ++r) {
        const int hr  = h0 - 1 + r;
        const int hrc = hr < 0 ? 0 : (hr > RF_H - 1 ? RF_H - 1 : hr);  // clamp
        const float* row = P + (hrc << 9);
        // Two dense float4 loads; halo columns from neighbor lanes via shfl.
        const floatx4 Bv = *reinterpret_cast<const floatx4*>(row + w0);
        const floatx4 Cv = *reinterpret_cast<const floatx4*>(row + w0 + 4);
        const float left  = __shfl_up(Cv.w, 1);    // lane-1's row[w0-1]
        const float right = __shfl_down(Bv.x, 1);  // lane+1's row[w0+8]
        // Zero-pad mask for out-of-range rows (wave-uniform: strip uniform).
        const float zf = (hr < 0 || hr >= RF_H) ? 0.0f : 1.0f;

        float w_[10];
        w_[0] = left * mA * zf;
        w_[1] = Bv.x * zf; w_[2] = Bv.y * zf; w_[3] = Bv.z * zf; w_[4] = Bv.w * zf;
        w_[5] = Cv.x * zf; w_[6] = Cv.y * zf; w_[7] = Cv.z * zf; w_[8] = Cv.w * zf;
        w_[9] = right * mD * zf;

        #pragma unroll
        for (int o = 0; o < 4; ++o) {
            const int kr = r - o;              // compile-time after unroll
            if (kr >= 0 && kr <= 2) {
                const float k0 = wgt[kr][0], k1 = wgt[kr][1], k2 = wgt[kr][2];
                #pragma unroll
                for (int j = 0; j < 8; ++j)
                    acc[o][j] += k0 * w_[j] + k1 * w_[j + 1] + k2 * w_[j + 2];
            }
        }
    }

    // Finite inputs -> reference's where(isnan,1.0) is dead; just clip.
    float* outP = out + plane * (RF_H * RF_W) + w0;
    #pragma unroll
    for (int o = 0; o < 4; ++o) {
        floatx4 lo, hi;
        lo.x = fminf(fmaxf(acc[o][0], 0.0f), 1.0f);
        lo.y = fminf(fmaxf(acc[o][1], 0.0f), 1.0f);
        lo.z = fminf(fmaxf(acc[o][2], 0.0f), 1.0f);
        lo.w = fminf(fmaxf(acc[o][3], 0.0f), 1.0f);
        hi.x = fminf(fmaxf(acc[o][4], 0.0f), 1.0f);
        hi.y = fminf(fmaxf(acc[o][5], 0.0f), 1.0f);
        hi.z = fminf(fmaxf(acc[o][6], 0.0f), 1.0f);
        hi.w = fminf(fmaxf(acc[o][7], 0.0f), 1.0f);
        float* orow = outP + ((h0 + o) << 9);
        *reinterpret_cast<floatx4*>(orow)     = lo;
        *reinterpret_cast<floatx4*>(orow + 4) = hi;
    }
}

extern "C" void kernel_launch(void* const* d_in, const int* in_sizes, int n_in,
                              void* d_out, int out_size, void* d_ws, size_t ws_size,
                              hipStream_t stream) {
    const float* img   = (const float*)d_in[0];
    const float* noise = (const float*)d_in[1];
    float* out = (float*)d_out;

    // 96 planes * 128 strips * 64 col-groups = 786,432 threads = 3072 blocks
    const int grid = 96 * 128 * 64 / 256;
    RandomFilter_40767829574170_kernel<<<grid, 256, 0, stream>>>(img, noise, out);
}